// Round 1
// baseline (38278.976 us; speedup 1.0000x reference)
//
#include <hip/hip_runtime.h>

// ---------------------------------------------------------------------------
// RevRNN: T=2056 sequential steps; each step: 2x GEMM [64,514]x[514,512] with
// batch-mean centering. Persistent kernel, 32 worker WGs (column-partitioned),
// register-resident W fragments, fp16 MFMA (fp32 accum), fp32 raw state in LDS,
// 2 grid barriers per step (agent-scope atomic counter).
// ---------------------------------------------------------------------------

#define NWG 32
#define T_TOT 2056
#define S_SEQ 2048
#define HF 256
#define DIN 514

typedef _Float16 f16x8 __attribute__((ext_vector_type(8)));
typedef float f32x4 __attribute__((ext_vector_type(4)));

// transpose+convert x [B][S][F] f32 -> xh [t][b][f] f16 (coalesced both sides)
__global__ void cvt_x_kernel(const float* __restrict__ x,
                             _Float16* __restrict__ xh) {
  const int t = (int)(blockIdx.x >> 6);
  const int b = (int)(blockIdx.x & 63);
  const float v = x[((size_t)b * S_SEQ + t) * 256 + threadIdx.x];
  xh[((size_t)blockIdx.x) * 256 + threadIdx.x] = (_Float16)v;
}

__launch_bounds__(256, 1)
__global__ void rnn_kernel(const float* __restrict__ xg,
                           const float* __restrict__ hs,
                           const float* __restrict__ W0,
                           const float* __restrict__ W1,
                           float* __restrict__ out,
                           unsigned* __restrict__ ctr,
                           _Float16* __restrict__ sC0,
                           _Float16* __restrict__ sC1,
                           const _Float16* __restrict__ xh,
                           int use_xh) {
  // worker selection: blocks 0,8,16,... (likely same XCD under %8 round-robin;
  // correctness does not depend on placement)
  if ((blockIdx.x & 7) != 0) return;
  const int wg = (int)(blockIdx.x >> 3);   // 0..31
  const int tid = (int)threadIdx.x;
  const int wv = tid >> 6;                 // wave 0..3 (16 batch rows each)
  const int ln = tid & 63;
  const int n = ln & 15;                   // packed col (B/C frag); A-frag row
  const int kq = ln >> 4;                  // quad 0..3
  const int c0 = wg * 8;                   // first calc column owned
  const int ba = wv * 16 + n;              // A-operand batch row
  const int brow0 = wv * 16 + kq * 4;      // C-frag first batch row

  __shared__ float raw[2][64][8];          // [half][batch][own col] fp32 state
  __shared__ float colsum[4][8];           // per-wave column sums

  // packed col n<8 -> W row c0+n (relu6 input z0); n>=8 -> W row 256+c0+n-8 (tanh z1)
  const int wrow = (n < 8) ? (c0 + n) : (HF + c0 + (n - 8));

  // ---- preload W fragments into registers (loop-invariant) ----
  f16x8 w0f[16], w1f[16];
  float pw0a, pw0b, pw1a, pw1b;
  {
    const float* r0 = W0 + (size_t)wrow * DIN;
    const float* r1 = W1 + (size_t)wrow * DIN;
#pragma unroll
    for (int kk = 0; kk < 16; ++kk) {
      const int k0 = kk * 32 + kq * 8;
      f16x8 a, b;
#pragma unroll
      for (int j = 0; j < 8; ++j) {
        a[j] = (_Float16)r0[k0 + j];
        b[j] = (_Float16)r1[k0 + j];
      }
      w0f[kk] = a;
      w1f[kk] = b;
    }
    pw0a = r0[512]; pw0b = r0[513];   // pe weight columns, kept fp32
    pw1a = r1[512]; pw1b = r1[513];
  }

  // ---- init raw state; publish centered h0 (identical rows -> exactly 0) ----
  for (int idx = tid; idx < 512; idx += 256) {
    const int b = idx >> 3, j = idx & 7;
    raw[0][b][j] = hs[c0 + j];
    raw[1][b][j] = hs[HF + c0 + j];
    sC0[(size_t)b * HF + c0 + j] = (_Float16)0.f;
  }

  unsigned bar_target = 0;

#define GBAR()                                                                 \
  do {                                                                         \
    bar_target += NWG;                                                         \
    __syncthreads(); /* drains vmcnt: all block stores at L2 */                \
    if (tid == 0) {                                                            \
      __hip_atomic_fetch_add(ctr, 1u, __ATOMIC_RELEASE,                        \
                             __HIP_MEMORY_SCOPE_AGENT);                        \
      while (__hip_atomic_load(ctr, __ATOMIC_RELAXED,                          \
                               __HIP_MEMORY_SCOPE_AGENT) < bar_target) {       \
        __builtin_amdgcn_s_sleep(1);                                           \
      }                                                                        \
      __builtin_amdgcn_fence(__ATOMIC_ACQUIRE, "agent");                       \
    }                                                                          \
    __syncthreads();                                                           \
  } while (0)

// one half-step: GEMM (A=[centered state | x_t], B=W frags) + epilogue
// (pe term, relu6*tanh gate via xor-8 shuffle, 0.5 state update, batch mean,
//  publish centered fp16)
#define PHASE(WF, PWA, PWB, ASRC, HALF, DST)                                   \
  do {                                                                         \
    f32x4 acc0 = {0.f, 0.f, 0.f, 0.f};                                         \
    f32x4 acc1 = {0.f, 0.f, 0.f, 0.f};                                         \
    {                                                                          \
      const _Float16* Ah = (ASRC) + (size_t)ba * HF + kq * 8;                  \
      _Pragma("unroll")                                                        \
      for (int kk = 0; kk < 8; ++kk) {                                         \
        f16x8 af = *(const f16x8*)(Ah + kk * 32);                              \
        acc0 = __builtin_amdgcn_mfma_f32_16x16x32_f16(af, WF[kk], acc0, 0, 0, 0); \
      }                                                                        \
      if (have_x) {                                                            \
        if (use_xh) {                                                          \
          const _Float16* Ax = xh + (((size_t)t * 64 + ba) << 8) + kq * 8;     \
          _Pragma("unroll")                                                    \
          for (int kk = 0; kk < 8; ++kk) {                                     \
            f16x8 af = *(const f16x8*)(Ax + kk * 32);                          \
            acc1 = __builtin_amdgcn_mfma_f32_16x16x32_f16(af, WF[8 + kk], acc1, 0, 0, 0); \
          }                                                                    \
        } else {                                                               \
          const float* Axf = xg + ((size_t)ba * S_SEQ + t) * 256 + kq * 8;     \
          _Pragma("unroll")                                                    \
          for (int kk = 0; kk < 8; ++kk) {                                     \
            f16x8 af;                                                          \
            _Pragma("unroll")                                                  \
            for (int j = 0; j < 8; ++j) af[j] = (_Float16)Axf[kk * 32 + j];    \
            acc1 = __builtin_amdgcn_mfma_f32_16x16x32_f16(af, WF[8 + kk], acc1, 0, 0, 0); \
          }                                                                    \
        }                                                                      \
      }                                                                        \
    }                                                                          \
    const float peterm = pe0 * (PWA) + pe1 * (PWB);                            \
    float nv[4];                                                               \
    float ssum = 0.f;                                                          \
    _Pragma("unroll")                                                          \
    for (int r = 0; r < 4; ++r) {                                              \
      const float z = acc0[r] + acc1[r] + peterm;                              \
      const float p = __shfl_xor(z, 8);                                        \
      const float z0 = (n < 8) ? z : p;                                        \
      const float z1 = (n < 8) ? p : z;                                        \
      const float cv = fminf(fmaxf(z0, 0.f), 6.f) * tanhf(z1);                 \
      const float nvv = (raw[HALF][brow0 + r][n & 7] + cv) * 0.5f;             \
      nv[r] = nvv;                                                             \
      ssum += nvv;                                                             \
    }                                                                          \
    ssum += __shfl_xor(ssum, 16);                                              \
    ssum += __shfl_xor(ssum, 32);                                              \
    if (kq == 0 && n < 8) colsum[wv][n] = ssum;                                \
    __syncthreads();                                                           \
    const float mean = (colsum[0][n & 7] + colsum[1][n & 7] +                  \
                        colsum[2][n & 7] + colsum[3][n & 7]) * (1.f / 64.f);   \
    if (n < 8) {                                                               \
      _Pragma("unroll")                                                        \
      for (int r = 0; r < 4; ++r) {                                            \
        raw[HALF][brow0 + r][n] = nv[r];                                       \
        (DST)[(size_t)(brow0 + r) * HF + c0 + n] = (_Float16)(nv[r] - mean);   \
      }                                                                        \
    }                                                                          \
  } while (0)

  GBAR();  // init publish visible to all workers

  for (int t = 0; t < T_TOT; ++t) {
    const float pe0 = (float)(t + 1);
    const float pe1 = (pe0 - 1028.5f) * (1.0f / 1028.5f);
    const int have_x = (t < S_SEQ) ? 1 : 0;
    // o1_new = (h1 + calc(h0c, s, W0)) * 0.5 ; publish centered o1 -> sC1
    PHASE(w0f, pw0a, pw0b, sC0, 1, sC1);
    GBAR();
    // o0_new = (h0 + calc(o1c, s, W1)) * 0.5 ; publish centered o0 -> sC0
    PHASE(w1f, pw1a, pw1b, sC1, 0, sC0);
    GBAR();
  }

  // final h = [o0 | o1], fp32 out, each WG writes its own 16 columns
  for (int idx = tid; idx < 1024; idx += 256) {
    const int b = idx >> 4, cc = idx & 15;
    const int half = cc >> 3, j = cc & 7;
    out[(size_t)b * 512 + (size_t)half * HF + c0 + j] = raw[half][b][j];
  }

#undef PHASE
#undef GBAR
}

extern "C" void kernel_launch(void* const* d_in, const int* in_sizes, int n_in,
                              void* d_out, int out_size, void* d_ws, size_t ws_size,
                              hipStream_t stream) {
  (void)in_sizes; (void)n_in; (void)out_size;
  const float* x  = (const float*)d_in[0];
  const float* hs = (const float*)d_in[1];
  const float* W0 = (const float*)d_in[2];
  const float* W1 = (const float*)d_in[3];
  float* out = (float*)d_out;

  char* ws = (char*)d_ws;
  unsigned* ctr = (unsigned*)ws;                      // barrier counter @ 0
  _Float16* sC0 = (_Float16*)(ws + 4096);             // centered h0 state
  _Float16* sC1 = (_Float16*)(ws + 4096 + 32768);     // centered o1 state
  _Float16* xh  = (_Float16*)(ws + 69632);            // x transposed f16
  const size_t xh_bytes = (size_t)S_SEQ * 64 * 256 * 2;
  const int use_xh = (ws_size >= (size_t)69632 + xh_bytes) ? 1 : 0;

  hipMemsetAsync(d_ws, 0, 4096, stream);              // zero barrier counter
  if (use_xh) {
    cvt_x_kernel<<<dim3(S_SEQ * 64), dim3(256), 0, stream>>>(x, xh);
  }
  rnn_kernel<<<dim3(256), dim3(256), 0, stream>>>(x, hs, W0, W1, out, ctr,
                                                  sC0, sC1, xh, use_xh);
}

// Round 2
// 24929.016 us; speedup vs baseline: 1.5355x; 1.5355x over previous
//
#include <hip/hip_runtime.h>

// ---------------------------------------------------------------------------
// RevRNN persistent kernel, round 2.
// Change vs round 1: the grid barrier no longer uses release/acquire agent
// fences (those emit buffer_wbl2 + buffer_inv -> ~9us/phase of L2 cache
// maintenance). All cross-WG state (centered activations) moves via RELAXED
// agent-scope atomics (global_load/store sc0 sc1 -> LLC bypass, no fences).
// Per-WG flag words replace the fetch_add counter. x-part MFMAs are issued
// before the flag poll so the wait overlaps useful work.
// ---------------------------------------------------------------------------

#define NWG 32
#define T_TOT 2056
#define S_SEQ 2048
#define HF 256
#define DIN 514

typedef _Float16 f16x8 __attribute__((ext_vector_type(8)));
typedef float f32x4 __attribute__((ext_vector_type(4)));

// transpose+convert x [B][S][F] f32 -> xh [t][b][f] f16 (coalesced both sides)
__global__ void cvt_x_kernel(const float* __restrict__ x,
                             _Float16* __restrict__ xh) {
  const int t = (int)(blockIdx.x >> 6);
  const int b = (int)(blockIdx.x & 63);
  const float v = x[((size_t)b * S_SEQ + t) * 256 + threadIdx.x];
  xh[((size_t)blockIdx.x) * 256 + threadIdx.x] = (_Float16)v;
}

__launch_bounds__(256, 1)
__global__ void rnn_kernel(const float* __restrict__ xg,
                           const float* __restrict__ hs,
                           const float* __restrict__ W0,
                           const float* __restrict__ W1,
                           float* __restrict__ out,
                           unsigned* __restrict__ flags,
                           unsigned* __restrict__ sC0,
                           unsigned* __restrict__ sC1,
                           const _Float16* __restrict__ xh,
                           int use_xh) {
  if ((blockIdx.x & 7) != 0) return;
  const int wg = (int)(blockIdx.x >> 3);   // 0..31
  const int tid = (int)threadIdx.x;
  const int wv = tid >> 6;                 // wave 0..3 (16 batch rows each)
  const int ln = tid & 63;
  const int n = ln & 15;                   // packed col (C frag) / A row
  const int kq = ln >> 4;                  // quad 0..3
  const int c0 = wg * 8;                   // first owned calc column
  const int ba = wv * 16 + n;              // A-operand batch row
  const int brow0 = wv * 16 + kq * 4;      // C-frag first batch row

  __shared__ float raw[2][64][8];          // [half][batch][own col] fp32 state
  __shared__ float colsum[4][8];

  // packed col n<8 -> W row c0+n (relu6 arg); n>=8 -> W row 256+c0+n-8 (tanh arg)
  const int wrow = (n < 8) ? (c0 + n) : (HF + c0 + (n - 8));

  // ---- preload W fragments into registers (loop-invariant) ----
  f16x8 w0f[16], w1f[16];
  float pw0a, pw0b, pw1a, pw1b;
  {
    const float* r0 = W0 + (size_t)wrow * DIN;
    const float* r1 = W1 + (size_t)wrow * DIN;
#pragma unroll
    for (int kk = 0; kk < 16; ++kk) {
      const int k0 = kk * 32 + kq * 8;
      f16x8 a, b;
#pragma unroll
      for (int j = 0; j < 8; ++j) {
        a[j] = (_Float16)r0[k0 + j];
        b[j] = (_Float16)r1[k0 + j];
      }
      w0f[kk] = a;
      w1f[kk] = b;
    }
    pw0a = r0[512]; pw0b = r0[513];
    pw1a = r1[512]; pw1b = r1[513];
  }

  // ---- init raw state; publish centered h0 = 0 via LLC-bypass stores ----
  for (int idx = tid; idx < 512; idx += 256) {
    const int b = idx >> 3, j = idx & 7;
    raw[0][b][j] = hs[c0 + j];
    raw[1][b][j] = hs[HF + c0 + j];
  }
  {
    const int b = tid >> 2, dc = tid & 3;  // 256 dwords: 64 rows x 4 dwords
    __hip_atomic_store(sC0 + (size_t)b * (HF / 2) + (c0 >> 1) + dc, 0u,
                       __ATOMIC_RELAXED, __HIP_MEMORY_SCOPE_AGENT);
  }
  __syncthreads();  // waves drain vmcnt before barrier -> stores LLC-visible
  if (tid == 0)
    __hip_atomic_store(&flags[wg], 1u, __ATOMIC_RELAXED,
                       __HIP_MEMORY_SCOPE_AGENT);

// spin until all 32 WG flags reach tgt (lane i watches flag i)
#define POLL(tgt)                                                              \
  do {                                                                         \
    const unsigned tgtu = (unsigned)(tgt);                                     \
    for (;;) {                                                                 \
      unsigned f = 0xFFFFFFFFu;                                                \
      if (ln < NWG)                                                            \
        f = __hip_atomic_load(&flags[ln], __ATOMIC_RELAXED,                    \
                              __HIP_MEMORY_SCOPE_AGENT);                       \
      if (__ballot(f >= tgtu) == ~0ull) break;                                 \
    }                                                                          \
  } while (0)

// one half-step. ph = global phase index (0..2T-1).
#define PHASE(WF, PWA, PWB, SRC, HALF, DST, ph)                                \
  do {                                                                         \
    f32x4 acc = {0.f, 0.f, 0.f, 0.f};                                          \
    if (have_x) { /* x part first: independent of the flag */                  \
      if (use_xh) {                                                            \
        const _Float16* Ax = xh + (((size_t)t * 64 + ba) << 8) + kq * 8;       \
        _Pragma("unroll")                                                      \
        for (int kk = 0; kk < 8; ++kk) {                                       \
          f16x8 af = *(const f16x8*)(Ax + kk * 32);                            \
          acc = __builtin_amdgcn_mfma_f32_16x16x32_f16(af, WF[8 + kk], acc,    \
                                                       0, 0, 0);               \
        }                                                                      \
      } else {                                                                 \
        const float* Axf = xg + ((size_t)ba * S_SEQ + t) * 256 + kq * 8;       \
        _Pragma("unroll")                                                      \
        for (int kk = 0; kk < 8; ++kk) {                                       \
          f16x8 af;                                                            \
          _Pragma("unroll")                                                    \
          for (int j = 0; j < 8; ++j) af[j] = (_Float16)Axf[kk * 32 + j];      \
          acc = __builtin_amdgcn_mfma_f32_16x16x32_f16(af, WF[8 + kk], acc,    \
                                                       0, 0, 0);               \
        }                                                                      \
      }                                                                        \
    }                                                                          \
    POLL((ph) + 1);                                                            \
    { /* state part: LLC-bypass loads, then 8 MFMAs */                         \
      const unsigned* Sp = (SRC) + (size_t)ba * (HF / 2) + kq * 4;             \
      union { unsigned u[4]; f16x8 h; } cv[8];                                 \
      _Pragma("unroll")                                                        \
      for (int kk = 0; kk < 8; ++kk) {                                         \
        _Pragma("unroll")                                                      \
        for (int d = 0; d < 4; ++d)                                            \
          cv[kk].u[d] = __hip_atomic_load(                                     \
              (unsigned*)(Sp + kk * 16 + d), __ATOMIC_RELAXED,                 \
              __HIP_MEMORY_SCOPE_AGENT);                                       \
      }                                                                        \
      _Pragma("unroll")                                                        \
      for (int kk = 0; kk < 8; ++kk)                                           \
        acc = __builtin_amdgcn_mfma_f32_16x16x32_f16(cv[kk].h, WF[kk], acc,    \
                                                     0, 0, 0);                 \
    }                                                                          \
    const float peterm = pe0 * (PWA) + pe1 * (PWB);                            \
    float nv[4];                                                               \
    float ssum = 0.f;                                                          \
    _Pragma("unroll")                                                          \
    for (int r = 0; r < 4; ++r) {                                              \
      const float z = acc[r] + peterm;                                         \
      const float p = __shfl_xor(z, 8);                                        \
      const float z0 = (n < 8) ? z : p;                                        \
      const float z1 = (n < 8) ? p : z;                                        \
      const float cvv = fminf(fmaxf(z0, 0.f), 6.f) * tanhf(z1);                \
      const float nvv = (raw[HALF][brow0 + r][n & 7] + cvv) * 0.5f;            \
      nv[r] = nvv;                                                             \
      ssum += nvv;                                                             \
    }                                                                          \
    ssum += __shfl_xor(ssum, 16);                                              \
    ssum += __shfl_xor(ssum, 32);                                              \
    if (kq == 0 && n < 8) colsum[wv][n] = ssum;                                \
    __syncthreads();                                                           \
    const float mean = (colsum[0][n & 7] + colsum[1][n & 7] +                  \
                        colsum[2][n & 7] + colsum[3][n & 7]) * (1.f / 64.f);   \
    _Pragma("unroll")                                                          \
    for (int r = 0; r < 4; ++r) {                                              \
      union { _Float16 h; unsigned short us; } hb;                             \
      hb.h = (_Float16)(nv[r] - mean);                                         \
      const unsigned part = (unsigned)__shfl_xor((int)hb.us, 1) & 0xFFFFu;     \
      if (n < 8) {                                                             \
        raw[HALF][brow0 + r][n] = nv[r];                                       \
        if ((n & 1) == 0) { /* even col stores packed pair */                  \
          const unsigned dw = (unsigned)hb.us | (part << 16);                  \
          __hip_atomic_store(                                                  \
              (DST) + (((size_t)(brow0 + r) * HF + c0 + n) >> 1), dw,          \
              __ATOMIC_RELAXED, __HIP_MEMORY_SCOPE_AGENT);                     \
        }                                                                      \
      }                                                                        \
    }                                                                          \
    __syncthreads(); /* per-wave vmcnt(0) drain -> all stores LLC-visible */   \
    if (tid == 0)                                                              \
      __hip_atomic_store(&flags[wg], (unsigned)((ph) + 2), __ATOMIC_RELAXED,   \
                         __HIP_MEMORY_SCOPE_AGENT);                            \
  } while (0)

  for (int t = 0; t < T_TOT; ++t) {
    const float pe0 = (float)(t + 1);
    const float pe1 = (pe0 - 1028.5f) * (1.0f / 1028.5f);
    const int have_x = (t < S_SEQ) ? 1 : 0;
    PHASE(w0f, pw0a, pw0b, sC0, 1, sC1, 2 * t);      // o1 = (h1 + calc)*0.5
    PHASE(w1f, pw1a, pw1b, sC1, 0, sC0, 2 * t + 1);  // o0 = (h0 + calc)*0.5
  }

  // final h = [o0 | o1]; raw[] writes are ordered before the last syncthreads
  for (int idx = tid; idx < 1024; idx += 256) {
    const int b = idx >> 4, cc = idx & 15;
    const int half = cc >> 3, j = cc & 7;
    out[(size_t)b * 512 + (size_t)half * HF + c0 + j] = raw[half][b][j];
  }

#undef PHASE
#undef POLL
}

extern "C" void kernel_launch(void* const* d_in, const int* in_sizes, int n_in,
                              void* d_out, int out_size, void* d_ws, size_t ws_size,
                              hipStream_t stream) {
  (void)in_sizes; (void)n_in; (void)out_size;
  const float* x  = (const float*)d_in[0];
  const float* hs = (const float*)d_in[1];
  const float* W0 = (const float*)d_in[2];
  const float* W1 = (const float*)d_in[3];
  float* out = (float*)d_out;

  char* ws = (char*)d_ws;
  unsigned* flags = (unsigned*)ws;                    // 32 flag words @ 0
  unsigned* sC0 = (unsigned*)(ws + 4096);             // centered h0 (f16 pairs)
  unsigned* sC1 = (unsigned*)(ws + 4096 + 32768);     // centered o1 (f16 pairs)
  _Float16* xh  = (_Float16*)(ws + 69632);            // x transposed f16
  const size_t xh_bytes = (size_t)S_SEQ * 64 * 256 * 2;
  const int use_xh = (ws_size >= (size_t)69632 + xh_bytes) ? 1 : 0;

  hipMemsetAsync(d_ws, 0, 4096, stream);              // zero flags
  if (use_xh) {
    cvt_x_kernel<<<dim3(S_SEQ * 64), dim3(256), 0, stream>>>(x, xh);
  }
  rnn_kernel<<<dim3(256), dim3(256), 0, stream>>>(x, hs, W0, W1, out, flags,
                                                  sC0, sC1, xh, use_xh);
}

// Round 3
// 21630.396 us; speedup vs baseline: 1.7697x; 1.1525x over previous
//
#include <hip/hip_runtime.h>

// ---------------------------------------------------------------------------
// RevRNN persistent kernel, round 3.
// Partition: 4 batch-groups (16 rows) x 8 col-groups (32 o-cols) = 32 WGs.
// - W fragments register-resident (128 VGPRs), packed z0/z1 rows per tile.
// - Cross-WG state: uncentered f16 pairs via relaxed agent u64 loads (LLC).
// - Readiness + mean in ONE object: tag-packed u64 partial column sums
//   (hi32 = phase tag, lo32 = f32 sum of 16 rows). Each thread spins on its
//   own 32B -> no shared-line poll storm, single LLC round for flag+mean.
// - Producer path per-wave: state stores -> s_waitcnt vmcnt(0) -> tagged
//   partials. No producer barrier. Consumer: spin -> mean LDS -> sync ->
//   centered A-frags (v_pk f16 sub) -> 16 MFMAs -> gate -> publish.
// - x loads issued before the poll (latency hidden under spin), cvt'd once
//   per t, reused by both phases. Raw recurrence state in fp32 registers.
// ---------------------------------------------------------------------------

#define T_TOT 2056
#define S_SEQ 2048

typedef _Float16 f16x8 __attribute__((ext_vector_type(8)));
typedef float f32x4 __attribute__((ext_vector_type(4)));

__launch_bounds__(256, 1)
__global__ void rnn_kernel(const float* __restrict__ xg,
                           const float* __restrict__ hs,
                           const float* __restrict__ W0,
                           const float* __restrict__ W1,
                           float* __restrict__ out,
                           unsigned long long* __restrict__ partH0,
                           unsigned long long* __restrict__ partH1,
                           unsigned* __restrict__ state0,
                           unsigned* __restrict__ state1) {
  const int wgid = (int)blockIdx.x;        // 0..31
  const int b = wgid & 3;                  // batch group: rows 16b..16b+15
  const int c = wgid >> 2;                 // col group: o-cols 32c..32c+31
  const int tid = (int)threadIdx.x;
  const int wv = tid >> 6;                 // wave 0..3
  const int ln = tid & 63;
  const int n = ln & 15;                   // packed col in tile / A-row
  const int kq = ln >> 4;                  // quad 0..3
  const int ocol = c * 32 + wv * 8 + (n & 7);      // owned output column
  const int wrow = (n < 8) ? ocol : (256 + ocol);  // packed W row (z0|z1)
  const int arow = 16 * b + n;                     // A-fragment batch row

  __shared__ __align__(16) _Float16 mean_h[2][256];  // per-phase-parity mean

  // ---- preload W fragments (state part + x part) into registers ----
  f16x8 w0s[8], w0x[8], w1s[8], w1x[8];
  float w0pa, w0pb, w1pa, w1pb;
  {
    const float* r0 = W0 + (size_t)wrow * 514;
    const float* r1 = W1 + (size_t)wrow * 514;
#pragma unroll
    for (int kk = 0; kk < 8; ++kk) {
      const int k0 = kk * 32 + kq * 8;
      f16x8 a, bx, a1, bx1;
#pragma unroll
      for (int j = 0; j < 8; ++j) {
        a[j]   = (_Float16)r0[k0 + j];
        bx[j]  = (_Float16)r0[256 + k0 + j];
        a1[j]  = (_Float16)r1[k0 + j];
        bx1[j] = (_Float16)r1[256 + k0 + j];
      }
      w0s[kk] = a; w0x[kk] = bx; w1s[kk] = a1; w1x[kk] = bx1;
    }
    w0pa = r0[512]; w0pb = r0[513];
    w1pa = r1[512]; w1pb = r1[513];
  }

  // ---- raw recurrence state (fp32, register-resident) ----
  float raw0[4], raw1[4];
#pragma unroll
  for (int r = 0; r < 4; ++r) { raw0[r] = hs[ocol]; raw1[r] = hs[256 + ocol]; }

  // ---- init publish: uncentered h0 (f16 pairs) + tagged partials (tag 1) --
  if ((n & 1) == 0 && n < 8) {
    union { _Float16 h; unsigned short u; } e0, e1;
    e0.h = (_Float16)hs[ocol]; e1.h = (_Float16)hs[ocol + 1];
    const unsigned dw = (unsigned)e0.u | ((unsigned)e1.u << 16);
#pragma unroll
    for (int r = 0; r < 4; ++r)
      __hip_atomic_store(state0 + (size_t)(16 * b + kq * 4 + r) * 128 +
                             (ocol >> 1),
                         dw, __ATOMIC_RELAXED, __HIP_MEMORY_SCOPE_AGENT);
  }
  asm volatile("s_waitcnt vmcnt(0)" ::: "memory");
  if (kq == 0 && n < 8) {
    const float s = 16.f * hs[ocol];
    __hip_atomic_store(partH0 + (size_t)ocol * 4 + b,
                       (1ull << 32) | (unsigned long long)__float_as_uint(s),
                       __ATOMIC_RELAXED, __HIP_MEMORY_SCOPE_AGENT);
  }

// spin on this thread's column partials (4 b-groups, 32B); then mean -> LDS
#define POLLMEAN(PIN, TAG, PAR)                                                \
  {                                                                            \
    const unsigned long long* pp = (PIN) + 4 * tid;                            \
    unsigned long long q0, q1, q2, q3;                                         \
    const unsigned tg = (unsigned)(TAG);                                       \
    for (;;) {                                                                 \
      q0 = __hip_atomic_load(pp + 0, __ATOMIC_RELAXED,                         \
                             __HIP_MEMORY_SCOPE_AGENT);                        \
      q1 = __hip_atomic_load(pp + 1, __ATOMIC_RELAXED,                         \
                             __HIP_MEMORY_SCOPE_AGENT);                        \
      q2 = __hip_atomic_load(pp + 2, __ATOMIC_RELAXED,                         \
                             __HIP_MEMORY_SCOPE_AGENT);                        \
      q3 = __hip_atomic_load(pp + 3, __ATOMIC_RELAXED,                         \
                             __HIP_MEMORY_SCOPE_AGENT);                        \
      if ((unsigned)(q0 >> 32) >= tg && (unsigned)(q1 >> 32) >= tg &&          \
          (unsigned)(q2 >> 32) >= tg && (unsigned)(q3 >> 32) >= tg)            \
        break;                                                                 \
    }                                                                          \
    const float m = (__uint_as_float((unsigned)q0) +                           \
                     __uint_as_float((unsigned)q1) +                           \
                     __uint_as_float((unsigned)q2) +                           \
                     __uint_as_float((unsigned)q3)) * 0.015625f;               \
    mean_h[PAR][tid] = (_Float16)m;                                            \
  }                                                                            \
  __syncthreads();

// centered-state K-loop + gate + state/partial publish
#define TAIL(WS, SIN, SOUT, POUT, RAW, TAGOUT, PAR)                            \
  {                                                                            \
    const unsigned long long* sp =                                             \
        (const unsigned long long*)(SIN) + (size_t)arow * 64 + kq * 2;         \
    const _Float16* mh = &mean_h[PAR][kq * 8];                                 \
    _Pragma("unroll")                                                          \
    for (int kk = 0; kk < 8; ++kk) {                                           \
      union { unsigned long long q[2]; f16x8 v; } sv;                          \
      sv.q[0] = __hip_atomic_load(sp + kk * 8 + 0, __ATOMIC_RELAXED,           \
                                  __HIP_MEMORY_SCOPE_AGENT);                   \
      sv.q[1] = __hip_atomic_load(sp + kk * 8 + 1, __ATOMIC_RELAXED,           \
                                  __HIP_MEMORY_SCOPE_AGENT);                   \
      const f16x8 mv = *(const f16x8*)(mh + kk * 32);                          \
      const f16x8 av = sv.v - mv;                                              \
      acc = __builtin_amdgcn_mfma_f32_16x16x32_f16(av, WS[kk], acc, 0, 0, 0);  \
    }                                                                          \
    float nv[4], ssum = 0.f;                                                   \
    _Pragma("unroll")                                                          \
    for (int r = 0; r < 4; ++r) {                                              \
      const float z = acc[r];                                                  \
      const float p = __shfl_xor(z, 8);                                        \
      const float z0 = (n < 8) ? z : p;                                        \
      const float z1 = (n < 8) ? p : z;                                        \
      const float cv = fminf(fmaxf(z0, 0.f), 6.f) * tanhf(z1);                 \
      const float o = ((RAW)[r] + cv) * 0.5f;                                  \
      (RAW)[r] = o; nv[r] = o; ssum += o;                                      \
    }                                                                          \
    ssum += __shfl_xor(ssum, 16);                                              \
    ssum += __shfl_xor(ssum, 32);                                              \
    _Pragma("unroll")                                                          \
    for (int r = 0; r < 4; ++r) {                                              \
      union { _Float16 h; unsigned short u; } hb;                              \
      hb.h = (_Float16)nv[r];                                                  \
      const unsigned pr = (unsigned)__shfl_xor((int)hb.u, 1) & 0xFFFFu;        \
      if ((n & 1) == 0 && n < 8) {                                             \
        const unsigned dw = (unsigned)hb.u | (pr << 16);                       \
        __hip_atomic_store((SOUT) + (size_t)(16 * b + kq * 4 + r) * 128 +      \
                               (ocol >> 1),                                    \
                           dw, __ATOMIC_RELAXED, __HIP_MEMORY_SCOPE_AGENT);    \
      }                                                                        \
    }                                                                          \
    asm volatile("s_waitcnt vmcnt(0)" ::: "memory");                           \
    if (kq == 0 && n < 8)                                                      \
      __hip_atomic_store(                                                      \
          (POUT) + (size_t)ocol * 4 + b,                                       \
          ((unsigned long long)(unsigned)(TAGOUT) << 32) |                     \
              (unsigned long long)__float_as_uint(ssum),                       \
          __ATOMIC_RELAXED, __HIP_MEMORY_SCOPE_AGENT);                         \
  }

  f16x8 xa[8];
  for (int t = 0; t < T_TOT; ++t) {
    const float pe0 = (float)(t + 1);
    const float pe1 = (pe0 - 1028.5f) * (1.0f / 1028.5f);
    const int have_x = (t < S_SEQ);

    // issue x loads now; they complete while we spin in phase A's poll
    f32x4 xf[16];
    if (have_x) {
      const float* xp = xg + ((size_t)arow * S_SEQ + t) * 256 + kq * 8;
#pragma unroll
      for (int kk = 0; kk < 8; ++kk) {
        xf[2 * kk]     = *(const f32x4*)(xp + kk * 32);
        xf[2 * kk + 1] = *(const f32x4*)(xp + kk * 32 + 4);
      }
    }

    // ---------------- phase A: o1 = (h1 + calc(h0c, s, W0)) * 0.5 ----------
    {
      f32x4 acc;
      const float pt = pe0 * w0pa + pe1 * w0pb;
      acc[0] = pt; acc[1] = pt; acc[2] = pt; acc[3] = pt;
      POLLMEAN(partH0, 2 * t + 1, 0);
      if (have_x) {
#pragma unroll
        for (int kk = 0; kk < 8; ++kk) {
          f16x8 af;
#pragma unroll
          for (int j = 0; j < 4; ++j) {
            af[j]     = (_Float16)xf[2 * kk][j];
            af[4 + j] = (_Float16)xf[2 * kk + 1][j];
          }
          xa[kk] = af;
          acc = __builtin_amdgcn_mfma_f32_16x16x32_f16(af, w0x[kk], acc,
                                                       0, 0, 0);
        }
      }
      TAIL(w0s, state0, state1, partH1, raw1, 2 * t + 2, 0);
    }

    // ---------------- phase B: o0 = (h0 + calc(o1c, s, W1)) * 0.5 ----------
    {
      f32x4 acc;
      const float pt = pe0 * w1pa + pe1 * w1pb;
      acc[0] = pt; acc[1] = pt; acc[2] = pt; acc[3] = pt;
      if (have_x) {
#pragma unroll
        for (int kk = 0; kk < 8; ++kk)
          acc = __builtin_amdgcn_mfma_f32_16x16x32_f16(xa[kk], w1x[kk], acc,
                                                       0, 0, 0);
      }
      POLLMEAN(partH1, 2 * t + 2, 1);
      TAIL(w1s, state1, state0, partH0, raw0, 2 * t + 3, 1);
    }
  }

  // ---- final h = [o0 | o1] fp32 ----
  if (n < 8) {
#pragma unroll
    for (int r = 0; r < 4; ++r) {
      const int row = 16 * b + kq * 4 + r;
      out[(size_t)row * 512 + ocol] = raw0[r];
      out[(size_t)row * 512 + 256 + ocol] = raw1[r];
    }
  }

#undef TAIL
#undef POLLMEAN
}

extern "C" void kernel_launch(void* const* d_in, const int* in_sizes, int n_in,
                              void* d_out, int out_size, void* d_ws, size_t ws_size,
                              hipStream_t stream) {
  (void)in_sizes; (void)n_in; (void)out_size; (void)ws_size;
  const float* x  = (const float*)d_in[0];
  const float* hs = (const float*)d_in[1];
  const float* W0 = (const float*)d_in[2];
  const float* W1 = (const float*)d_in[3];
  float* out = (float*)d_out;

  char* ws = (char*)d_ws;
  unsigned long long* partH0 = (unsigned long long*)ws;            // 8 KB
  unsigned long long* partH1 = (unsigned long long*)(ws + 8192);   // 8 KB
  unsigned* state0 = (unsigned*)(ws + 16384);                      // 32 KB
  unsigned* state1 = (unsigned*)(ws + 49152);                      // 32 KB

  // zero the tagged partials (0xAA poison would read as a huge valid tag!)
  hipMemsetAsync(d_ws, 0, 16384, stream);
  rnn_kernel<<<dim3(32), dim3(256), 0, stream>>>(x, hs, W0, W1, out,
                                                 partH0, partH1, state0,
                                                 state1);
}